// Round 1
// baseline (93.433 us; speedup 1.0000x reference)
//
#include <hip/hip_runtime.h>
#include <math.h>

// Problem constants (B,C,H,W) = (16,256,80,80), GROUPS=32
constexpr int CG   = 8;            // channels per group
constexpr int Hh   = 80;
constexpr int Ww   = 80;
constexpr int HW   = Hh * Ww;      // 6400
constexpr int NG   = 16 * 32;      // B*GROUPS = 512 group-instances
constexpr int NCH  = NG * CG;      // 4096 total channels
constexpr int PP   = NCH * Hh;     // 327680 floats per pool/gate array
constexpr float EPSf = 1e-5f;

// Workspace layout (floats):
//  0*PP : mean_h   [bgc][h]
//  1*PP : mean_w   [bgc][w]
//  2*PP : max_h    [bgc][h]
//  3*PP : max_w    [bgc][w]
//  4*PP : sghx (mean-branch h-gate; scaled by coefX in K4)
//  5*PP : sgwx (mean-branch w-gate)
//  6*PP : sghy (max-branch h-gate; scaled by coefY in K4)
//  7*PP : sgwy (max-branch w-gate)
//  8*PP : stats [bgc][8]  (s1x,s2x,s1y,s2y,max_ty,min_ty,-,-)
//  KOFF : kconst [bg]
constexpr int STATS = 8 * PP;
constexpr int KOFF  = STATS + NCH * 8;
// total floats = KOFF + NG = 2,654,720  (~10.6 MB) — must fit in ws.

__device__ __forceinline__ float sigmoidf(float v) {
    return 1.0f / (1.0f + __expf(-v));
}

// ---------------- K1: per-channel row/col mean+max pools -------------------
__global__ __launch_bounds__(256) void k_pool(const float* __restrict__ x,
                                              float* __restrict__ ws) {
    const int bgc = blockIdx.x;                 // 0..4095
    const float* base = x + (size_t)bgc * HW;
    __shared__ float tile[Hh * 84];             // pad stride 84 (16B-aligned rows)

    for (int v = threadIdx.x; v < 1600; v += 256) {  // 1600 float4 = 6400 floats
        int h  = v / 20;                        // 20 float4 per row
        int w0 = (v % 20) * 4;
        float4 d = ((const float4*)base)[v];
        *(float4*)&tile[h * 84 + w0] = d;
    }
    __syncthreads();

    const int t = threadIdx.x;
    if (t < 80) {
        // row t: mean/max over w
        float s = 0.f, m = -INFINITY;
        const float4* r = (const float4*)&tile[t * 84];
        #pragma unroll
        for (int i = 0; i < 20; i++) {
            float4 d = r[i];
            s += d.x + d.y + d.z + d.w;
            m = fmaxf(m, fmaxf(fmaxf(d.x, d.y), fmaxf(d.z, d.w)));
        }
        ws[0 * PP + bgc * 80 + t] = s * (1.f / 80.f);
        ws[2 * PP + bgc * 80 + t] = m;
        // col t: mean/max over h
        float s2 = 0.f, m2 = -INFINITY;
        #pragma unroll 8
        for (int i = 0; i < 80; i++) {
            float v = tile[i * 84 + t];
            s2 += v;
            m2 = fmaxf(m2, v);
        }
        ws[1 * PP + bgc * 80 + t] = s2 * (1.f / 80.f);
        ws[3 * PP + bgc * 80 + t] = m2;
    }
}

// ---------------- K2: 8x8 conv + bias + sigmoid -> gates -------------------
__global__ __launch_bounds__(256) void k_gate(const float* __restrict__ conv_w,
                                              const float* __restrict__ conv_b,
                                              float* __restrict__ ws) {
    const int bg = blockIdx.x;                  // 0..511
    __shared__ float wsm[64];
    __shared__ float cbs[8];
    if (threadIdx.x < 64) wsm[threadIdx.x] = conv_w[threadIdx.x];
    if (threadIdx.x < 8)  cbs[threadIdx.x] = conv_b[threadIdx.x];
    __syncthreads();

    const float* mh = ws + 0 * PP + bg * 640;   // [c][h]
    const float* mw = ws + 1 * PP + bg * 640;
    const float* xh = ws + 2 * PP + bg * 640;
    const float* xw = ws + 3 * PP + bg * 640;

    for (int idx = threadIdx.x; idx < 2560; idx += 256) {
        const int br = idx / 1280;              // 0 = mean-branch, 1 = max-branch
        const int r  = idx % 1280;
        const int o  = r / 160;
        const int l  = r % 160;
        const float* ph = br ? xh : mh;
        const float* pw = br ? xw : mw;
        float acc = cbs[o];
        if (l < 80) {
            #pragma unroll
            for (int c = 0; c < 8; c++) acc += wsm[o * 8 + c] * ph[c * 80 + l];
        } else {
            const int w = l - 80;
            #pragma unroll
            for (int c = 0; c < 8; c++) acc += wsm[o * 8 + c] * pw[c * 80 + w];
        }
        const float s = sigmoidf(acc);
        if (l < 80) ws[(4 + 2 * br) * PP + bg * 640 + o * 80 + l]        = s;
        else        ws[(5 + 2 * br) * PP + bg * 640 + o * 80 + (l - 80)] = s;
    }
}

// ---------------- K3: per-channel gated-tensor statistics ------------------
__global__ __launch_bounds__(256) void k_stats(const float* __restrict__ x,
                                               float* __restrict__ ws) {
    const int bgc = blockIdx.x;                 // 0..4095
    __shared__ float g[4 * 80];                 // sghx, sgwx, sghy, sgwy for this channel
    for (int i = threadIdx.x; i < 320; i += 256) {
        const int a = i / 80, h = i % 80;
        g[i] = ws[(4 + a) * PP + bgc * 80 + h];
    }
    __syncthreads();

    const float* base = x + (size_t)bgc * HW;
    float s1x = 0.f, s2x = 0.f, s1y = 0.f, s2y = 0.f;
    float my = -INFINITY, ny = INFINITY;

    for (int i = 0; i < 7; i++) {
        const int v = threadIdx.x + i * 256;
        if (v < 1600) {
            const int h  = v / 20;
            const int w0 = (v % 20) * 4;
            float4 d = ((const float4*)base)[v];
            const float ghx = g[h], ghy = g[160 + h];
            float dd[4] = {d.x, d.y, d.z, d.w};
            #pragma unroll
            for (int j = 0; j < 4; j++) {
                const float tx = dd[j] * ghx * g[80 + w0 + j];
                const float ty = dd[j] * ghy * g[240 + w0 + j];
                s1x += tx; s2x += tx * tx;
                s1y += ty; s2y += ty * ty;
                my = fmaxf(my, ty); ny = fminf(ny, ty);
            }
        }
    }
    // wave reduce (width 64), then cross-wave via LDS
    #pragma unroll
    for (int off = 32; off > 0; off >>= 1) {
        s1x += __shfl_down(s1x, off);
        s2x += __shfl_down(s2x, off);
        s1y += __shfl_down(s1y, off);
        s2y += __shfl_down(s2y, off);
        my = fmaxf(my, __shfl_down(my, off));
        ny = fminf(ny, __shfl_down(ny, off));
    }
    __shared__ float red[4][6];
    const int wave = threadIdx.x >> 6, lane = threadIdx.x & 63;
    if (lane == 0) {
        red[wave][0] = s1x; red[wave][1] = s2x; red[wave][2] = s1y;
        red[wave][3] = s2y; red[wave][4] = my;  red[wave][5] = ny;
    }
    __syncthreads();
    if (threadIdx.x == 0) {
        float a0 = red[0][0], a1 = red[0][1], a2 = red[0][2], a3 = red[0][3];
        float a4 = red[0][4], a5 = red[0][5];
        for (int wv = 1; wv < 4; wv++) {
            a0 += red[wv][0]; a1 += red[wv][1]; a2 += red[wv][2]; a3 += red[wv][3];
            a4 = fmaxf(a4, red[wv][4]); a5 = fminf(a5, red[wv][5]);
        }
        float* st = ws + STATS + bgc * 8;
        st[0] = a0; st[1] = a1; st[2] = a2; st[3] = a3; st[4] = a4; st[5] = a5;
    }
}

// ------- K4: finalize stats, softmaxes, fold coefficients into gates -------
__global__ __launch_bounds__(64) void k_finalize(const float* __restrict__ gnw,
                                                 const float* __restrict__ gnb,
                                                 float* __restrict__ ws) {
    const int bg = blockIdx.x;                  // 0..511
    __shared__ float Ax[8], Bx[8], Ay[8], By[8], ymax[8];
    const int t = threadIdx.x;
    if (t < 8) {
        const float* st = ws + STATS + (bg * 8 + t) * 8;
        const float s1x = st[0], s2x = st[1], s1y = st[2], s3y = st[3];
        const float my = st[4], ny = st[5];
        const float w = gnw[t], b = gnb[t];
        const float mux  = s1x * (1.f / 6400.f);
        const float varx = s2x * (1.f / 6400.f) - mux * mux;
        const float ax   = rsqrtf(varx + EPSf) * w;
        Ax[t] = ax; Bx[t] = b - mux * ax;
        const float muy  = s1y * (1.f / 6400.f);
        const float vary = s3y * (1.f / 6400.f) - muy * muy;
        const float ay   = rsqrtf(vary + EPSf) * w;
        Ay[t] = ay; By[t] = b - muy * ay;
        ymax[t] = (ay >= 0.f ? my : ny) * ay + By[t];
    }
    __syncthreads();

    // x12 = softmax(gn_b)  (mean of a normalized tensor over its norm axes is 0)
    float x12[8], y12[8];
    {
        float mb = -INFINITY;
        for (int c = 0; c < 8; c++) mb = fmaxf(mb, gnb[c]);
        float se = 0.f;
        for (int c = 0; c < 8; c++) { x12[c] = __expf(gnb[c] - mb); se += x12[c]; }
        float inv = 1.f / se;
        for (int c = 0; c < 8; c++) x12[c] *= inv;
        float m2 = -INFINITY;
        for (int c = 0; c < 8; c++) m2 = fmaxf(m2, ymax[c]);
        se = 0.f;
        for (int c = 0; c < 8; c++) { y12[c] = __expf(ymax[c] - m2); se += y12[c]; }
        inv = 1.f / se;
        for (int c = 0; c < 8; c++) y12[c] *= inv;
    }
    // fold coefficients into h-gates:  chy = x12*Ay*sghy ; chx = y12*Ax*sghx
    for (int i = t; i < 640; i += 64) {
        const int c = i / 80;
        ws[6 * PP + bg * 640 + i] *= x12[c] * Ay[c];
        ws[4 * PP + bg * 640 + i] *= y12[c] * Ax[c];
    }
    if (t == 0) {
        float kc = 0.f;
        for (int c = 0; c < 8; c++) kc += x12[c] * By[c] + y12[c] * Bx[c];
        ws[KOFF + bg] = kc;
    }
}

// ---------------- K5: weights -> sigmoid -> output -------------------------
__global__ __launch_bounds__(256) void k_out(const float* __restrict__ x,
                                             const float* __restrict__ ws,
                                             float* __restrict__ out) {
    const int bg = blockIdx.x;                  // 0..511
    __shared__ float g[4 * 640];                // [a][c][h]: 0=chx,1=cwx,2=chy,3=cwy
    for (int i = threadIdx.x; i < 2560; i += 256) {
        const int a = i / 640, j = i % 640;
        g[i] = ws[(4 + a) * PP + bg * 640 + j];
    }
    const float kc = ws[KOFF + bg];
    __syncthreads();

    const float* base = x + (size_t)bg * CG * HW;
    float*       ob   = out + (size_t)bg * CG * HW;

    for (int i = 0; i < 7; i++) {
        const int v = threadIdx.x + i * 256;
        if (v < 1600) {
            const int h  = v / 20;
            const int w0 = (v % 20) * 4;
            float4 gxv[8];
            #pragma unroll
            for (int c = 0; c < 8; c++)
                gxv[c] = *(const float4*)(base + c * HW + v * 4);

            float s0 = kc, s1 = kc, s2 = kc, s3 = kc;
            #pragma unroll
            for (int c = 0; c < 8; c++) {
                const float chx = g[c * 80 + h];
                const float chy = g[1280 + c * 80 + h];
                const float* cwx = &g[640  + c * 80 + w0];
                const float* cwy = &g[1920 + c * 80 + w0];
                s0 += gxv[c].x * (chy * cwy[0] + chx * cwx[0]);
                s1 += gxv[c].y * (chy * cwy[1] + chx * cwx[1]);
                s2 += gxv[c].z * (chy * cwy[2] + chx * cwx[2]);
                s3 += gxv[c].w * (chy * cwy[3] + chx * cwx[3]);
            }
            s0 = sigmoidf(s0); s1 = sigmoidf(s1); s2 = sigmoidf(s2); s3 = sigmoidf(s3);
            #pragma unroll
            for (int c = 0; c < 8; c++) {
                float4 o;
                o.x = gxv[c].x * s0; o.y = gxv[c].y * s1;
                o.z = gxv[c].z * s2; o.w = gxv[c].w * s3;
                *(float4*)(ob + c * HW + v * 4) = o;
            }
        }
    }
}

extern "C" void kernel_launch(void* const* d_in, const int* in_sizes, int n_in,
                              void* d_out, int out_size, void* d_ws, size_t ws_size,
                              hipStream_t stream) {
    const float* x      = (const float*)d_in[0];
    const float* conv_w = (const float*)d_in[1];
    const float* conv_b = (const float*)d_in[2];
    const float* gn_w   = (const float*)d_in[3];
    const float* gn_b   = (const float*)d_in[4];
    float* out = (float*)d_out;
    float* ws  = (float*)d_ws;   // needs (KOFF+NG)*4 ≈ 10.6 MB

    k_pool    <<<NCH, 256, 0, stream>>>(x, ws);
    k_gate    <<<NG,  256, 0, stream>>>(conv_w, conv_b, ws);
    k_stats   <<<NCH, 256, 0, stream>>>(x, ws);
    k_finalize<<<NG,   64, 0, stream>>>(gn_w, gn_b, ws);
    k_out     <<<NG,  256, 0, stream>>>(x, ws, out);
}

// Round 2
// 84.404 us; speedup vs baseline: 1.1070x; 1.1070x over previous
//
#include <hip/hip_runtime.h>
#include <math.h>

// Problem constants (B,C,H,W) = (16,256,80,80), GROUPS=32
constexpr int CG   = 8;            // channels per group
constexpr int Hh   = 80;
constexpr int Ww   = 80;
constexpr int HW   = Hh * Ww;      // 6400
constexpr int NG   = 16 * 32;      // B*GROUPS = 512 group-instances
constexpr int NCH  = NG * CG;      // 4096 total channels
constexpr int PP   = NCH * Hh;     // 327680 floats per pool array
constexpr float EPSf = 1e-5f;

// Workspace layout (floats):
//  0*PP : mean_h   [bgc][h]
//  1*PP : mean_w   [bgc][w]
//  2*PP : max_h    [bgc][h]
//  3*PP : max_w    [bgc][w]
//  4*PP : stats [bgc][8]  (s1x,s2x,s1y,s2y,max_ty,min_ty,-,-)
constexpr int STATS = 4 * PP;
// total floats = STATS + NCH*8 ≈ 1.34M (~5.4 MB)

__device__ __forceinline__ float sigmoidf(float v) {
    return 1.0f / (1.0f + __expf(-v));
}

// ---------------- K1: per-channel row/col mean+max pools -------------------
__global__ __launch_bounds__(256) void k_pool(const float* __restrict__ x,
                                              float* __restrict__ ws) {
    const int bgc = blockIdx.x;                 // 0..4095
    const float* base = x + (size_t)bgc * HW;
    __shared__ float tile[Hh * 84];             // pad stride 84 (16B-aligned rows)

    for (int v = threadIdx.x; v < 1600; v += 256) {  // 1600 float4 = 6400 floats
        int h  = v / 20;                        // 20 float4 per row
        int w0 = (v % 20) * 4;
        float4 d = ((const float4*)base)[v];
        *(float4*)&tile[h * 84 + w0] = d;
    }
    __syncthreads();

    const int t = threadIdx.x;
    if (t < 80) {
        // row t: mean/max over w  (waves 0-1)
        float s = 0.f, m = -INFINITY;
        const float4* r = (const float4*)&tile[t * 84];
        #pragma unroll
        for (int i = 0; i < 20; i++) {
            float4 d = r[i];
            s += d.x + d.y + d.z + d.w;
            m = fmaxf(m, fmaxf(fmaxf(d.x, d.y), fmaxf(d.z, d.w)));
        }
        ws[0 * PP + bgc * 80 + t] = s * (1.f / 80.f);
        ws[2 * PP + bgc * 80 + t] = m;
    } else if (t >= 128 && t < 208) {
        // col (t-128): mean/max over h  (waves 2-3)
        const int c = t - 128;
        float s2 = 0.f, m2 = -INFINITY;
        #pragma unroll 8
        for (int i = 0; i < 80; i++) {
            float v = tile[i * 84 + c];
            s2 += v;
            m2 = fmaxf(m2, v);
        }
        ws[1 * PP + bgc * 80 + c] = s2 * (1.f / 80.f);
        ws[3 * PP + bgc * 80 + c] = m2;
    }
}

// ---------- K2: per-channel gated-tensor statistics (inline conv) ----------
__global__ __launch_bounds__(256) void k_stats(const float* __restrict__ x,
                                               const float* __restrict__ conv_w,
                                               const float* __restrict__ conv_b,
                                               float* __restrict__ ws) {
    const int bgc = blockIdx.x;                 // 0..4095
    const int bg = bgc >> 3, o = bgc & 7;
    __shared__ float wsm[64];
    __shared__ float cbs[8];
    __shared__ float g[4 * 80];                 // sghx, sgwx, sghy, sgwy for channel o
    if (threadIdx.x < 64) wsm[threadIdx.x] = conv_w[threadIdx.x];
    if (threadIdx.x < 8)  cbs[threadIdx.x] = conv_b[threadIdx.x];
    __syncthreads();

    // inline 8->1 conv + sigmoid for this channel's 4 gate vectors
    for (int i = threadIdx.x; i < 320; i += 256) {
        const int a = i / 80, p = i % 80;       // a: 0=mh,1=mw,2=xh,3=xw
        const float* pool = ws + a * PP + bg * 640;
        float acc = cbs[o];
        #pragma unroll
        for (int c = 0; c < 8; c++) acc += wsm[o * 8 + c] * pool[c * 80 + p];
        g[i] = sigmoidf(acc);
    }
    __syncthreads();

    const float* base = x + (size_t)bgc * HW;
    float s1x = 0.f, s2x = 0.f, s1y = 0.f, s2y = 0.f;
    float my = -INFINITY, ny = INFINITY;

    for (int i = 0; i < 7; i++) {
        const int v = threadIdx.x + i * 256;
        if (v < 1600) {
            const int h  = v / 20;
            const int w0 = (v % 20) * 4;
            float4 d = ((const float4*)base)[v];
            const float ghx = g[h], ghy = g[160 + h];
            float dd[4] = {d.x, d.y, d.z, d.w};
            #pragma unroll
            for (int j = 0; j < 4; j++) {
                const float tx = dd[j] * ghx * g[80 + w0 + j];
                const float ty = dd[j] * ghy * g[240 + w0 + j];
                s1x += tx; s2x += tx * tx;
                s1y += ty; s2y += ty * ty;
                my = fmaxf(my, ty); ny = fminf(ny, ty);
            }
        }
    }
    #pragma unroll
    for (int off = 32; off > 0; off >>= 1) {
        s1x += __shfl_down(s1x, off);
        s2x += __shfl_down(s2x, off);
        s1y += __shfl_down(s1y, off);
        s2y += __shfl_down(s2y, off);
        my = fmaxf(my, __shfl_down(my, off));
        ny = fminf(ny, __shfl_down(ny, off));
    }
    __shared__ float red[4][6];
    const int wave = threadIdx.x >> 6, lane = threadIdx.x & 63;
    if (lane == 0) {
        red[wave][0] = s1x; red[wave][1] = s2x; red[wave][2] = s1y;
        red[wave][3] = s2y; red[wave][4] = my;  red[wave][5] = ny;
    }
    __syncthreads();
    if (threadIdx.x == 0) {
        float a0 = red[0][0], a1 = red[0][1], a2 = red[0][2], a3 = red[0][3];
        float a4 = red[0][4], a5 = red[0][5];
        for (int wv = 1; wv < 4; wv++) {
            a0 += red[wv][0]; a1 += red[wv][1]; a2 += red[wv][2]; a3 += red[wv][3];
            a4 = fmaxf(a4, red[wv][4]); a5 = fminf(a5, red[wv][5]);
        }
        float* st = ws + STATS + bgc * 8;
        st[0] = a0; st[1] = a1; st[2] = a2; st[3] = a3; st[4] = a4; st[5] = a5;
    }
}

// -------- K3: finalize (inline) + weights -> sigmoid -> output -------------
__global__ __launch_bounds__(256) void k_out(const float* __restrict__ x,
                                             const float* __restrict__ conv_w,
                                             const float* __restrict__ conv_b,
                                             const float* __restrict__ gnw,
                                             const float* __restrict__ gnb,
                                             const float* __restrict__ ws,
                                             float* __restrict__ out) {
    const int bg = blockIdx.x;                  // 0..511
    __shared__ float wsm[64];
    __shared__ float cbs[8];
    __shared__ float g[4 * 640];                // [a][c][h]: 0=chx,1=cwx,2=chy,3=cwy
    __shared__ float Axs[8], Bxs[8], Ays[8], Bys[8], ymaxs[8];
    __shared__ float cHx[8], cHy[8];            // y12*Ax , x12*Ay
    __shared__ float kcs;
    if (threadIdx.x < 64) wsm[threadIdx.x] = conv_w[threadIdx.x];
    if (threadIdx.x < 8)  cbs[threadIdx.x] = conv_b[threadIdx.x];
    __syncthreads();

    // all 8 channels x 4 gate vectors for this group (inline conv + sigmoid)
    for (int i = threadIdx.x; i < 2560; i += 256) {
        const int a = i / 640, c = (i % 640) / 80, p = i % 80;
        const float* pool = ws + a * PP + bg * 640;
        float acc = cbs[c];
        #pragma unroll
        for (int cc = 0; cc < 8; cc++) acc += wsm[c * 8 + cc] * pool[cc * 80 + p];
        g[i] = sigmoidf(acc);
    }
    // per-channel affine-norm constants
    if (threadIdx.x < 8) {
        const int t = threadIdx.x;
        const float* st = ws + STATS + (bg * 8 + t) * 8;
        const float s1x = st[0], s2x = st[1], s1y = st[2], s2y = st[3];
        const float my = st[4], ny = st[5];
        const float w = gnw[t], b = gnb[t];
        const float mux  = s1x * (1.f / 6400.f);
        const float varx = s2x * (1.f / 6400.f) - mux * mux;
        const float ax   = rsqrtf(varx + EPSf) * w;
        Axs[t] = ax; Bxs[t] = b - mux * ax;
        const float muy  = s1y * (1.f / 6400.f);
        const float vary = s2y * (1.f / 6400.f) - muy * muy;
        const float ay   = rsqrtf(vary + EPSf) * w;
        Ays[t] = ay; Bys[t] = b - muy * ay;
        ymaxs[t] = (ay >= 0.f ? my : ny) * ay + Bys[t];
    }
    __syncthreads();
    if (threadIdx.x == 0) {
        // x12 = softmax(gn_b): mean over the norm axes of a normalized tensor
        // is exactly gn_b. y12 = softmax over channels of max(y1).
        float x12[8], y12[8];
        float mb = -INFINITY;
        for (int c = 0; c < 8; c++) mb = fmaxf(mb, gnb[c]);
        float se = 0.f;
        for (int c = 0; c < 8; c++) { x12[c] = __expf(gnb[c] - mb); se += x12[c]; }
        float inv = 1.f / se;
        for (int c = 0; c < 8; c++) x12[c] *= inv;
        float m2 = -INFINITY;
        for (int c = 0; c < 8; c++) m2 = fmaxf(m2, ymaxs[c]);
        se = 0.f;
        for (int c = 0; c < 8; c++) { y12[c] = __expf(ymaxs[c] - m2); se += y12[c]; }
        inv = 1.f / se;
        float kc = 0.f;
        for (int c = 0; c < 8; c++) {
            y12[c] *= inv;
            cHx[c] = y12[c] * Axs[c];
            cHy[c] = x12[c] * Ays[c];
            kc += x12[c] * Bys[c] + y12[c] * Bxs[c];
        }
        kcs = kc;
    }
    __syncthreads();
    // fold coefficients into the h-gates
    for (int i = threadIdx.x; i < 1280; i += 256) {
        if (i < 640) g[i]        *= cHx[i / 80];
        else         g[640 + i]  *= cHy[(i - 640) / 80];   // g[1280..1919]
    }
    __syncthreads();

    const float kc = kcs;
    const float* base = x + (size_t)bg * CG * HW;
    float*       ob   = out + (size_t)bg * CG * HW;

    for (int i = 0; i < 7; i++) {
        const int v = threadIdx.x + i * 256;
        if (v < 1600) {
            const int h  = v / 20;
            const int w0 = (v % 20) * 4;
            float4 gxv[8];
            #pragma unroll
            for (int c = 0; c < 8; c++)
                gxv[c] = *(const float4*)(base + c * HW + v * 4);

            float s0 = kc, s1 = kc, s2 = kc, s3 = kc;
            #pragma unroll
            for (int c = 0; c < 8; c++) {
                const float chx = g[c * 80 + h];
                const float chy = g[1280 + c * 80 + h];
                const float* cwx = &g[640  + c * 80 + w0];
                const float* cwy = &g[1920 + c * 80 + w0];
                s0 += gxv[c].x * (chy * cwy[0] + chx * cwx[0]);
                s1 += gxv[c].y * (chy * cwy[1] + chx * cwx[1]);
                s2 += gxv[c].z * (chy * cwy[2] + chx * cwx[2]);
                s3 += gxv[c].w * (chy * cwy[3] + chx * cwx[3]);
            }
            s0 = sigmoidf(s0); s1 = sigmoidf(s1); s2 = sigmoidf(s2); s3 = sigmoidf(s3);
            #pragma unroll
            for (int c = 0; c < 8; c++) {
                float4 o;
                o.x = gxv[c].x * s0; o.y = gxv[c].y * s1;
                o.z = gxv[c].z * s2; o.w = gxv[c].w * s3;
                *(float4*)(ob + c * HW + v * 4) = o;
            }
        }
    }
}

extern "C" void kernel_launch(void* const* d_in, const int* in_sizes, int n_in,
                              void* d_out, int out_size, void* d_ws, size_t ws_size,
                              hipStream_t stream) {
    const float* x      = (const float*)d_in[0];
    const float* conv_w = (const float*)d_in[1];
    const float* conv_b = (const float*)d_in[2];
    const float* gn_w   = (const float*)d_in[3];
    const float* gn_b   = (const float*)d_in[4];
    float* out = (float*)d_out;
    float* ws  = (float*)d_ws;   // needs ~5.4 MB

    k_pool <<<NCH, 256, 0, stream>>>(x, ws);
    k_stats<<<NCH, 256, 0, stream>>>(x, conv_w, conv_b, ws);
    k_out  <<<NG,  256, 0, stream>>>(x, conv_w, conv_b, gn_w, gn_b, ws, out);
}

// Round 3
// 69.802 us; speedup vs baseline: 1.3386x; 1.2092x over previous
//
#include <hip/hip_runtime.h>
#include <math.h>

// (B,C,H,W) = (16,256,80,80), GROUPS=32 -> 512 group-instances of 8x80x80
constexpr int CG = 8;
constexpr int HW = 6400;           // 80*80
constexpr int NG = 512;            // B*GROUPS
constexpr float EPSf = 1e-5f;

__device__ __forceinline__ float sigmoidf(float v) {
    return 1.0f / (1.0f + __expf(-v));
}

// One block per group-instance. 512 threads (8 waves).
// Phases: A) per-channel tile -> row/col mean+max pools (cold HBM read)
//         B) 8x8 conv + sigmoid -> 4x8x80 gates (LDS)
//         C) per-channel stats of gated tensors (global re-read, L2/L3 hit)
//         D) finalize affine-norm constants, softmaxes, fold coefs into gates
//         E) weights -> sigmoid -> output (global re-read + HBM write)
__global__ __launch_bounds__(512, 4) void k_fused(
    const float* __restrict__ x,
    const float* __restrict__ conv_w,
    const float* __restrict__ conv_b,
    const float* __restrict__ gnw,
    const float* __restrict__ gnb,
    float* __restrict__ out)
{
    const int bg  = blockIdx.x;            // 0..511
    const int tid = threadIdx.x;           // 0..511

    __shared__ float tile[80 * 84];        // one channel, padded stride 84
    __shared__ float pools[4 * 640];       // [a][c][p]: a0=mh a1=mw a2=xh a3=xw
    __shared__ float g[4 * 640];           // gates, same [a][c][p] layout
    __shared__ float wsm[64];
    __shared__ float cbs[8];
    __shared__ float stats[8][8];          // per channel: s1x,s2x,s1y,s2y,my,ny
    __shared__ float Axs[8], Bxs[8], Ays[8], Bys[8], ymaxs[8], cHx[8], cHy[8];
    __shared__ float kcs;

    if (tid < 64) wsm[tid] = conv_w[tid];
    if (tid < 8)  cbs[tid] = conv_b[tid];

    const float* base = x + (size_t)bg * CG * HW;

    // ---------------- Phase A: pools, one channel at a time ----------------
    for (int c = 0; c < 8; ++c) {
        __syncthreads();                   // tile readers of prev iter done
        for (int i = 0; i < 4; ++i) {
            const int v = tid + i * 512;   // float4 index within channel
            if (v < 1600) {
                float4 d = ((const float4*)(base + c * HW))[v];
                const int h = v / 20, w0 = (v % 20) * 4;
                *(float4*)&tile[h * 84 + w0] = d;
            }
        }
        __syncthreads();
        if (tid < 320) {
            const int r = tid >> 2, q = tid & 3;
            // row r: mean/max over w (each of 4 lanes does 5 float4)
            float s = 0.f, m = -INFINITY;
            const float4* rp = (const float4*)&tile[r * 84];
            #pragma unroll
            for (int k = q * 5; k < q * 5 + 5; ++k) {
                float4 d = rp[k];
                s += d.x + d.y + d.z + d.w;
                m = fmaxf(m, fmaxf(fmaxf(d.x, d.y), fmaxf(d.z, d.w)));
            }
            s += __shfl_down(s, 2, 4); s += __shfl_down(s, 1, 4);
            m = fmaxf(m, __shfl_down(m, 2, 4));
            m = fmaxf(m, __shfl_down(m, 1, 4));
            if (q == 0) {
                pools[0 * 640 + c * 80 + r] = s * (1.f / 80.f);
                pools[2 * 640 + c * 80 + r] = m;
            }
            // col r: mean/max over h (each of 4 lanes does 20 rows)
            float s2 = 0.f, m2 = -INFINITY;
            #pragma unroll 4
            for (int hh = q * 20; hh < q * 20 + 20; ++hh) {
                const float vv = tile[hh * 84 + r];
                s2 += vv;
                m2 = fmaxf(m2, vv);
            }
            s2 += __shfl_down(s2, 2, 4); s2 += __shfl_down(s2, 1, 4);
            m2 = fmaxf(m2, __shfl_down(m2, 2, 4));
            m2 = fmaxf(m2, __shfl_down(m2, 1, 4));
            if (q == 0) {
                pools[1 * 640 + c * 80 + r] = s2 * (1.f / 80.f);
                pools[3 * 640 + c * 80 + r] = m2;
            }
        }
    }
    __syncthreads();

    // ---------------- Phase B: gates = sigmoid(conv(pools)) ----------------
    for (int i = 0; i < 5; ++i) {
        const int e = tid + i * 512;
        if (e < 2560) {
            const int a = e / 640, rem = e % 640, c = rem / 80, p = rem % 80;
            float acc = cbs[c];
            #pragma unroll
            for (int cc = 0; cc < 8; ++cc)
                acc += wsm[c * 8 + cc] * pools[a * 640 + cc * 80 + p];
            g[e] = sigmoidf(acc);
        }
    }
    __syncthreads();

    // ---------------- Phase C: per-channel gated stats (one wave each) -----
    {
        const int c = tid >> 6, lane = tid & 63;
        const float* cb_ = base + c * HW;
        float s1x = 0.f, s2x = 0.f, s1y = 0.f, s2y = 0.f;
        float my = -INFINITY, ny = INFINITY;
        for (int j = 0; j < 25; ++j) {
            const int v = lane + j * 64;               // exactly covers 1600
            float4 d = ((const float4*)cb_)[v];
            const int h = v / 20, w0 = (v % 20) * 4;
            const float ghx = g[0 * 640 + c * 80 + h];
            const float ghy = g[2 * 640 + c * 80 + h];
            const float4 gwx = *(const float4*)&g[1 * 640 + c * 80 + w0];
            const float4 gwy = *(const float4*)&g[3 * 640 + c * 80 + w0];
            const float dd[4]  = {d.x, d.y, d.z, d.w};
            const float gx4[4] = {gwx.x, gwx.y, gwx.z, gwx.w};
            const float gy4[4] = {gwy.x, gwy.y, gwy.z, gwy.w};
            #pragma unroll
            for (int k = 0; k < 4; ++k) {
                const float tx = dd[k] * ghx * gx4[k];
                const float ty = dd[k] * ghy * gy4[k];
                s1x += tx; s2x += tx * tx;
                s1y += ty; s2y += ty * ty;
                my = fmaxf(my, ty); ny = fminf(ny, ty);
            }
        }
        #pragma unroll
        for (int off = 32; off > 0; off >>= 1) {
            s1x += __shfl_down(s1x, off);
            s2x += __shfl_down(s2x, off);
            s1y += __shfl_down(s1y, off);
            s2y += __shfl_down(s2y, off);
            my = fmaxf(my, __shfl_down(my, off));
            ny = fminf(ny, __shfl_down(ny, off));
        }
        if (lane == 0) {
            stats[c][0] = s1x; stats[c][1] = s2x; stats[c][2] = s1y;
            stats[c][3] = s2y; stats[c][4] = my;  stats[c][5] = ny;
        }
    }
    __syncthreads();

    // ---------------- Phase D: finalize + fold coefficients ----------------
    if (tid < 8) {
        const float s1x = stats[tid][0], s2x = stats[tid][1];
        const float s1y = stats[tid][2], s2y = stats[tid][3];
        const float my  = stats[tid][4], ny  = stats[tid][5];
        const float w = gnw[tid], b = gnb[tid];
        const float mux  = s1x * (1.f / 6400.f);
        const float varx = s2x * (1.f / 6400.f) - mux * mux;
        const float ax   = rsqrtf(varx + EPSf) * w;
        Axs[tid] = ax; Bxs[tid] = b - mux * ax;
        const float muy  = s1y * (1.f / 6400.f);
        const float vary = s2y * (1.f / 6400.f) - muy * muy;
        const float ay   = rsqrtf(vary + EPSf) * w;
        Ays[tid] = ay; Bys[tid] = b - muy * ay;
        ymaxs[tid] = (ay >= 0.f ? my : ny) * ay + Bys[tid];
    }
    __syncthreads();
    if (tid == 0) {
        // x12 = softmax(gn_b): the HW-mean of a tensor normalized over HW is
        // exactly gn_b. y12 = softmax over channels of max(y1).
        float x12[8], y12[8];
        float mb = -INFINITY;
        for (int c = 0; c < 8; ++c) mb = fmaxf(mb, gnb[c]);
        float se = 0.f;
        for (int c = 0; c < 8; ++c) { x12[c] = __expf(gnb[c] - mb); se += x12[c]; }
        float inv = 1.f / se;
        for (int c = 0; c < 8; ++c) x12[c] *= inv;
        float m2 = -INFINITY;
        for (int c = 0; c < 8; ++c) m2 = fmaxf(m2, ymaxs[c]);
        se = 0.f;
        for (int c = 0; c < 8; ++c) { y12[c] = __expf(ymaxs[c] - m2); se += y12[c]; }
        inv = 1.f / se;
        float kc = 0.f;
        for (int c = 0; c < 8; ++c) {
            y12[c] *= inv;
            cHx[c] = y12[c] * Axs[c];   // scales mean-branch h-gate
            cHy[c] = x12[c] * Ays[c];   // scales max-branch  h-gate
            kc += x12[c] * Bys[c] + y12[c] * Bxs[c];
        }
        kcs = kc;
    }
    __syncthreads();
    for (int i = 0; i < 3; ++i) {
        const int e = tid + i * 512;
        if (e < 1280) {
            if (e < 640) g[e]                 *= cHx[e / 80];         // a=0
            else         g[1280 + (e - 640)]  *= cHy[(e - 640) / 80]; // a=2
        }
    }
    __syncthreads();

    // ---------------- Phase E: weights -> sigmoid -> output ----------------
    const float kc = kcs;
    float* ob = out + (size_t)bg * CG * HW;
    for (int i = 0; i < 4; ++i) {
        const int v = tid + i * 512;
        if (v < 1600) {
            const int h = v / 20, w0 = (v % 20) * 4;
            float4 gxv[8];
            #pragma unroll
            for (int c = 0; c < 8; ++c)
                gxv[c] = *(const float4*)(base + c * HW + v * 4);

            float s0 = kc, s1 = kc, s2 = kc, s3 = kc;
            #pragma unroll
            for (int c = 0; c < 8; ++c) {
                const float chx = g[0 * 640 + c * 80 + h];
                const float chy = g[2 * 640 + c * 80 + h];
                const float4 cwx = *(const float4*)&g[1 * 640 + c * 80 + w0];
                const float4 cwy = *(const float4*)&g[3 * 640 + c * 80 + w0];
                s0 += gxv[c].x * (chy * cwy.x + chx * cwx.x);
                s1 += gxv[c].y * (chy * cwy.y + chx * cwx.y);
                s2 += gxv[c].z * (chy * cwy.z + chx * cwx.z);
                s3 += gxv[c].w * (chy * cwy.w + chx * cwx.w);
            }
            s0 = sigmoidf(s0); s1 = sigmoidf(s1);
            s2 = sigmoidf(s2); s3 = sigmoidf(s3);
            #pragma unroll
            for (int c = 0; c < 8; ++c) {
                float4 o;
                o.x = gxv[c].x * s0; o.y = gxv[c].y * s1;
                o.z = gxv[c].z * s2; o.w = gxv[c].w * s3;
                *(float4*)(ob + c * HW + v * 4) = o;
            }
        }
    }
}

extern "C" void kernel_launch(void* const* d_in, const int* in_sizes, int n_in,
                              void* d_out, int out_size, void* d_ws, size_t ws_size,
                              hipStream_t stream) {
    const float* x      = (const float*)d_in[0];
    const float* conv_w = (const float*)d_in[1];
    const float* conv_b = (const float*)d_in[2];
    const float* gn_w   = (const float*)d_in[3];
    const float* gn_b   = (const float*)d_in[4];
    float* out = (float*)d_out;
    (void)d_ws; (void)ws_size;

    k_fused<<<NG, 512, 0, stream>>>(x, conv_w, conv_b, gn_w, gn_b, out);
}